// Round 6
// baseline (219.795 us; speedup 1.0000x reference)
//
#include <hip/hip_runtime.h>
#include <cstdint>
#include <cstddef>

typedef unsigned short u16;
typedef unsigned int   u32;
typedef __attribute__((ext_vector_type(4))) float  f32x4;
typedef __attribute__((ext_vector_type(2))) float  f32x2;
typedef __attribute__((ext_vector_type(2))) u32    u32x2;
typedef __attribute__((ext_vector_type(8))) __bf16 bf16x8;

#define PSW   1056    // fallback: staged padded-image row width
#define ASTR  72      // fallback LDS row stride
#define CFW   4128    // Cfull row stride (elems); data cols 0..4119, zeros to 4127

// ws layout (bytes)
#define WS_BT  0u
#define WS_CF  1048576u                       // Bt: 512*1024*2
#define WS_AB  (1048576u + 16908288u)         // Cfull: 64*32*4128*2
#define WS_NEED (1048576u + 16908288u + 4194304u)  // + Abound: 64*32*512*4

static __device__ __forceinline__ float b2f(u32 u) {
  union { u32 i; float f; } c; c.i = u << 16; return c.f;
}
static __device__ __forceinline__ u16 f2b(float f) {
  union { float f; u32 i; } c; c.f = f;
  return (u16)((c.i + 0x7FFFu + ((c.i >> 16) & 1u)) >> 16);  // RNE
}

// async global->LDS DMA. LDS dest is WAVE-UNIFORM base + lane*size (m104).
static __device__ __forceinline__ void gl_lds16(const void* g, void* l) {
  __builtin_amdgcn_global_load_lds(
      (__attribute__((address_space(1))) unsigned int*)(void*)g,
      (__attribute__((address_space(3))) unsigned int*)l, 16, 0, 0);
}
static __device__ __forceinline__ void gl_lds4(const void* g, void* l) {
  __builtin_amdgcn_global_load_lds(
      (__attribute__((address_space(1))) unsigned int*)(void*)g,
      (__attribute__((address_space(3))) unsigned int*)l, 4, 0, 0);
}

// ---- standalone transpose (small-ws fallback path only)
__global__ __launch_bounds__(256) void transpose_w(const float* __restrict__ lw,
                                                   u16* __restrict__ bt) {
  __shared__ u16 tile[64][65];
  const int t  = threadIdx.x;
  const int c  = t & 63, r0 = t >> 6;
  const int n0 = blockIdx.x * 64;
  const int k0 = blockIdx.y * 64;
#pragma unroll
  for (int rr = 0; rr < 16; ++rr) {
    const int r = r0 * 16 + rr;
    tile[r][c] = f2b(lw[(size_t)(k0 + r) * 512 + n0 + c]);
  }
  __syncthreads();
#pragma unroll
  for (int rr = 0; rr < 16; ++rr) {
    const int r = r0 * 16 + rr;
    bt[(size_t)(n0 + r) * 1024 + k0 + c] = tile[c][r];
  }
}

// ---- kernel 1 (rewrite 3): barrier-free conv+bias+relu -> Cfull + Abound.
// One block per (b,h) output row, 2048 blocks = 8/CU, 256 thr, no LDS staging,
// no barriers: direct f32x4 global reads (3x vertical re-read is L2/L3-hot;
// HBM fetch stays ~1x img). This is the r4 fused_all phase-1 body (verified)
// re-hosted standalone. Blocks 2048..2055 transpose lin_w -> Bt.
// XCD-bijective swizzle: XCD x owns b in [8x,8x+8), h-adjacent ids same XCD.
__global__ __launch_bounds__(256) void prep3(
    const float* __restrict__ img, const float* __restrict__ cw,
    const float* __restrict__ cb, u16* __restrict__ cf, u32* __restrict__ ab,
    const float* __restrict__ lw, u16* __restrict__ bt)
{
  __shared__ __align__(16) u16 tile[64 * 65];   // transpose branch only (8.3KB)
  const int t  = threadIdx.x;
  const int id = blockIdx.x;

  if (id >= 2048) {
    // ---- transpose lin_w (fp32 K=1024 x N=512) -> Bt (bf16 N=512 x K=1024)
    const int c = t & 63, r0 = t >> 6;          // r0 in [0,4)
    for (int q = 0; q < 16; ++q) {
      const int T  = (id - 2048) * 16 + q;      // 128 tiles over 8 blocks
      const int n0 = (T & 7) << 6, k0 = (T >> 3) << 6;
      __syncthreads();
#pragma unroll
      for (int rr = 0; rr < 16; ++rr) {
        const int r = r0 * 16 + rr;
        tile[r * 65 + c] = f2b(lw[(size_t)(k0 + r) * 512 + n0 + c]);
      }
      __syncthreads();
#pragma unroll
      for (int rr = 0; rr < 16; ++rr) {
        const int r = r0 * 16 + rr;
        bt[(size_t)(n0 + r) * 1024 + k0 + c] = tile[c * 65 + r];
      }
    }
    return;
  }

  const int wg = ((id & 7) << 8) + (id >> 3);   // bijective, 2048%8==0
  const int bb = wg >> 5, hh = wg & 31;
  const float* imgb = img + (size_t)bb * 32 * 4096;
  float w9[9];
#pragma unroll
  for (int q = 0; q < 9; ++q) w9[q] = cw[q];
  const float bias = cb[0];

  u16* cfrow = cf + (size_t)(bb * 32 + hh) * CFW;

  // chunk c: outputs x in [8c,8c+8); window = padded coords [8c-4,8c+12)
  // (coord p <-> img col p-12; p<12 / 4108<=p<4120 pad 1.0; p>=4120 slack 0.0;
  //  dead rows skip == add 0.0 == conv's vertical zero padding).
  auto CONV8 = [&](int c) {
    float o[8];
#pragma unroll
    for (int j = 0; j < 8; ++j) o[j] = bias;
#pragma unroll
    for (int dr = 0; dr < 3; ++dr) {
      const int hr = hh - 1 + dr;
      if (hr < 0 || hr > 31) continue;
      const float* rp = imgb + (ptrdiff_t)hr * 4096;
      float win[16];
      if (c >= 2 && c < 512) {                  // fully interior: 4x f32x4
        const f32x4* vp = (const f32x4*)(rp + (c << 3) - 16);
        *(f32x4*)&win[0]  = vp[0];
        *(f32x4*)&win[4]  = vp[1];
        *(f32x4*)&win[8]  = vp[2];
        *(f32x4*)&win[12] = vp[3];
      } else {                                  // edge: clamped scalar+select
#pragma unroll
        for (int k2 = 0; k2 < 16; ++k2) {
          const int p  = (c << 3) - 4 + k2;
          int ci = p - 12; ci = ci < 0 ? 0 : (ci > 4095 ? 4095 : ci);
          const float v = rp[ci];
          win[k2] = (p < 12) ? 1.0f : (p >= 4120 ? 0.0f : (p >= 4108 ? 1.0f : v));
        }
      }
      const float w0 = w9[dr * 3], w1 = w9[dr * 3 + 1], w2 = w9[dr * 3 + 2];
#pragma unroll
      for (int j = 0; j < 8; ++j)
        o[j] += w0 * win[j + 3] + w1 * win[j + 4] + w2 * win[j + 5];
    }
    u32 pk[4];
#pragma unroll
    for (int q = 0; q < 4; ++q)
      pk[q] = (u32)f2b(fmaxf(o[2 * q], 0.f)) |
              ((u32)f2b(fmaxf(o[2 * q + 1], 0.f)) << 16);
    *(uint4*)(cfrow + (c << 3)) = make_uint4(pk[0], pk[1], pk[2], pk[3]);
  };

  CONV8(t);
  CONV8(t + 256);
  if (t < 3) CONV8(512 + t);                    // outputs 4096..4119
  if (t == 3) *(uint4*)(cfrow + 4120) = make_uint4(0u, 0u, 0u, 0u);

  // Abound: slice s, col j=0 (coords 8s,8s+1) and j=31 (coords 8s+30,8s+31)
  u32* abrow = ab + (size_t)(bb * 32 + hh) * 512;
#pragma unroll
  for (int ss = 0; ss < 2; ++ss) {
    const int s = t + (ss << 8);
    float o0 = bias, o1 = bias;
#pragma unroll
    for (int dr = 0; dr < 3; ++dr) {
      const int hr = hh - 1 + dr;
      if (hr < 0 || hr > 31) continue;
      const float* rp = imgb + (ptrdiff_t)hr * 4096;
      float p0, p1, q0, q1;
      if (s >= 2)   { f32x2 v = *(const f32x2*)(rp + (s << 3) - 12); p0 = v.x; p1 = v.y; }
      else          { p0 = 1.0f; p1 = 1.0f; }
      if (s <= 509) { f32x2 v = *(const f32x2*)(rp + (s << 3) + 18); q0 = v.x; q1 = v.y; }
      else          { q0 = 1.0f; q1 = 1.0f; }
      o0 += w9[dr * 3 + 1] * p0 + w9[dr * 3 + 2] * p1;
      o1 += w9[dr * 3]     * q0 + w9[dr * 3 + 1] * q1;
    }
    abrow[s] = (u32)f2b(fmaxf(o0, 0.f)) | ((u32)f2b(fmaxf(o1, 0.f)) << 16);
  }
}

// ---- kernel 2: GEMM (M=32768,K=1024,N=512), M-tile 64, 2048 blocks = 8/CU.
// r1 vs r2 showed time ~ 1/(blocks per CU): inter-block phase-offset overlap
// hides the per-K-step vmcnt(0) drain. LDS 19072B, acc[2][4].
// XCD-aware bijective swizzle (2048 = 8*256): XCD x owns b in [8x,8x+8).
__global__ __launch_bounds__(256) void gemm_k2(
    const u16* __restrict__ cf, const u32* __restrict__ ab,
    const u16* __restrict__ bt, const float* __restrict__ lb,
    float* __restrict__ out)
{
  // Ps [2][544] u16 (2176B) | Ab32 [2][64] u32 (512B) | Bs 128x64 swz u16 (16384B)
  __shared__ __align__(16) char sm[2176 + 512 + 16384];
  u16* Ps   = (u16*)sm;
  u32* Ab32 = (u32*)(sm + 2176);
  u16* Bs   = (u16*)(sm + 2688);
  float* Cs = (float*)sm;          // epilogue reuse [32][132] = 16896B

  const int t  = threadIdx.x;
  const int orig = blockIdx.y * 4 + blockIdx.x;          // hw linear id
  const int wg   = ((orig & 7) << 8) + (orig >> 3);      // bijective, 2048%8==0
  const int nt = wg & 3, mt = wg >> 2;                   // mt in [0,512)
  const int b  = mt >> 3, sg = mt & 7;                   // 64-slice group sg
  const int n0 = nt << 7;
  const int w  = t >> 6, i = t & 63;
  const int wr = w >> 1, wc = w & 1;
  const int lq = i >> 4, lr = i & 15;

  // B staging: chunk q = w*256 + j*64 + i -> n = w*32 + j*8 + (i>>3), c = (i&7)^((i>>3)&7)
  const int cB = (i & 7) ^ ((i >> 3) & 7);
  const u16* btp = bt + (size_t)(n0 + (w << 5) + (i >> 3)) * 1024 + (cB << 3);
  u16* BsW = Bs + (w << 11);                    // wave-uniform, + j*512 elems per call

  // Ps staging: 136 chunks (2 rows x 68), q = t (t<136)
  const int rP  = (t >= 68) ? 1 : 0;
  const int ccP = t - 68 * rP;
  const u16* cfp = cf + (size_t)(b * 32 + rP) * CFW + (sg << 9) + (ccP << 3);
  u16* PsW = (u16*)((char*)Ps + (w << 10));     // wave-uniform byte base

  // Ab staging: 128 dwords, d = t (t<128): row t>>6, slice t&63
  const u32* abp = ab + (size_t)(b * 32 + (t >> 6)) * 512 + (sg << 6) + (t & 63);
  u32* AbW = Ab32 + (w << 6);                   // wave-uniform

  f32x4 acc[2][4];
#pragma unroll
  for (int a = 0; a < 2; ++a)
#pragma unroll
    for (int c = 0; c < 4; ++c) acc[a][c] = (f32x4)0.0f;

  for (int kk = 0; kk < 16; ++kk) {
    __syncthreads();                 // all waves done reading prev tiles
    gl_lds16(btp,              BsW);
    gl_lds16(btp +  8 * 1024,  BsW + 512);
    gl_lds16(btp + 16 * 1024,  BsW + 1024);
    gl_lds16(btp + 24 * 1024,  BsW + 1536);
    if (t < 136) gl_lds16(cfp, PsW);
    if (t < 128) gl_lds4(abp, AbW);
    btp += 64; cfp += 2 * CFW; abp += 1024;
    __syncthreads();                 // drains vmcnt(0): DMA complete

#pragma unroll
    for (int kc = 0; kc < 2; ++kc) {
      const int bswz = (((kc << 2) + lq) ^ (lr & 7)) << 3;
      bf16x8 af[2], bfv[4];
#pragma unroll
      for (int im = 0; im < 2; ++im) {
        const int ml = wr * 32 + im * 16 + lr;
        af[im] = __builtin_bit_cast(bf16x8,
            *(const uint4*)(Ps + kc * 544 + ((ml + lq) << 3)));
        const u32 a32 = Ab32[kc * 64 + ml];    // same addr for 4 lq -> broadcast
        union { u16 u; __bf16 h; } lo, hi;
        lo.u = (u16)(a32 & 0xffffu); hi.u = (u16)(a32 >> 16);
        if (lq == 0) af[im][0] = lo.h;         // slice col j=0
        if (lq == 3) af[im][7] = hi.h;         // slice col j=31
      }
#pragma unroll
      for (int jn = 0; jn < 4; ++jn) {
        const int n = wc * 64 + jn * 16 + lr;
        bfv[jn] = __builtin_bit_cast(bf16x8, *(const uint4*)(Bs + (n << 6) + bswz));
      }
#pragma unroll
      for (int im = 0; im < 2; ++im)
#pragma unroll
        for (int jn = 0; jn < 4; ++jn)
          acc[im][jn] = __builtin_amdgcn_mfma_f32_16x16x32_bf16(
              af[im], bfv[jn], acc[im][jn], 0, 0, 0);
    }
  }

  // epilogue: +lin_b, LDS transpose, coalesced float4 row stores
  float lbv[4];
#pragma unroll
  for (int jn = 0; jn < 4; ++jn) lbv[jn] = lb[n0 + wc * 64 + jn * 16 + lr];

  const int erow = t >> 3, ecol = (t & 7) << 4;
  const int grow_base = (mt << 6) + ((erow >> 4) * 32) + (erow & 15);

#pragma unroll
  for (int im = 0; im < 2; ++im) {
    __syncthreads();
#pragma unroll
    for (int jn = 0; jn < 4; ++jn) {
      const int cl = wc * 64 + jn * 16 + lr;
#pragma unroll
      for (int r = 0; r < 4; ++r)
        Cs[(wr * 16 + lq * 4 + r) * 132 + cl] = acc[im][jn][r] + lbv[jn];
    }
    __syncthreads();
    const size_t grow = (size_t)(grow_base + im * 16);
    float* orow = out + grow * 512 + n0 + ecol;
    const float* crow = Cs + erow * 132 + ecol;
#pragma unroll
    for (int p = 0; p < 4; ++p)
      *(f32x4*)(orow + p * 4) = *(const f32x4*)(crow + p * 4);
  }
}

// ================= small-ws fallback (needs only 1MB ws) =================
__global__ __launch_bounds__(256) void fused_fallback(
    const float* __restrict__ img, const float* __restrict__ cw,
    const float* __restrict__ cb, const u16* __restrict__ bt,
    const float* __restrict__ lb, float* __restrict__ out)
{
  __shared__ __align__(16) u16 Ps[4 * PSW];
  __shared__ __align__(16) u16 As[128 * ASTR];
  __shared__ __align__(16) u16 Bs[128 * ASTR];
  const int t = threadIdx.x, nt = blockIdx.x, mt = blockIdx.y;
  const int b = mt >> 2, s0 = (mt & 3) << 7, X0 = s0 << 3, n0 = nt << 7;
  const float* imgb = img + (size_t)b * 32 * 4096;
  float cwf[9];
#pragma unroll
  for (int q = 0; q < 9; ++q) cwf[q] = cw[q];
  const float bias = cb[0];
  const int wv = t >> 6, l = t & 63;
  const int wr = wv >> 1, wc = wv & 1, lq = l >> 4, lr = l & 15;
  const int sl = t >> 1, hsel = t & 1;
  f32x4 acc[4][4];
#pragma unroll
  for (int a = 0; a < 4; ++a)
#pragma unroll
    for (int c = 0; c < 4; ++c) acc[a][c] = (f32x4)0.0f;
  for (int kk = 0; kk < 16; ++kk) {
    const int h0 = kk << 1;
    __syncthreads();
    uint4 bsv[4];
#pragma unroll
    for (int p = 0; p < 4; ++p) {
      const int idx8 = t + (p << 8);
      const int n = idx8 >> 3, k8 = idx8 & 7;
      bsv[p] = *(const uint4*)(bt + (size_t)(n0 + n) * 1024 + (kk << 6) + (k8 << 3));
    }
    for (int idx = t; idx < 4 * PSW; idx += 256) {
      const int r = idx / PSW, xi = idx - r * PSW;
      const int h = h0 - 1 + r, x = X0 - 1 + xi;
      u16 v = 0;
      if (h >= 0 && h < 32 && x >= 0 && x < 4120)
        v = (x < 12 || x >= 4108) ? (u16)0x3F80 : f2b(imgb[h * 4096 + (x - 12)]);
      Ps[idx] = v;
    }
    __syncthreads();
    {
      const int pbase = (sl << 3);
#pragma unroll
      for (int wb = 0; wb < 32; wb += 16) {
        float o[16];
#pragma unroll
        for (int j = 0; j < 16; ++j) o[j] = bias;
#pragma unroll
        for (int dr = 0; dr < 3; ++dr) {
          const u16* p = Ps + (hsel + dr) * PSW + pbase + wb;
          const uint4 va = *(const uint4*)p;
          const uint4 vb = *(const uint4*)(p + 8);
          const u32   vc = *(const u32*)(p + 16);
          float win[18];
          win[0] = b2f(va.x & 0xffffu); win[1] = b2f(va.x >> 16);
          win[2] = b2f(va.y & 0xffffu); win[3] = b2f(va.y >> 16);
          win[4] = b2f(va.z & 0xffffu); win[5] = b2f(va.z >> 16);
          win[6] = b2f(va.w & 0xffffu); win[7] = b2f(va.w >> 16);
          win[8] = b2f(vb.x & 0xffffu); win[9] = b2f(vb.x >> 16);
          win[10] = b2f(vb.y & 0xffffu); win[11] = b2f(vb.y >> 16);
          win[12] = b2f(vb.z & 0xffffu); win[13] = b2f(vb.z >> 16);
          win[14] = b2f(vb.w & 0xffffu); win[15] = b2f(vb.w >> 16);
          win[16] = b2f(vc & 0xffffu);   win[17] = b2f(vc >> 16);
          if (wb == 0) win[0] = 0.f; else win[17] = 0.f;
          const float w0 = cwf[dr * 3], w1 = cwf[dr * 3 + 1], w2 = cwf[dr * 3 + 2];
#pragma unroll
          for (int j = 0; j < 16; ++j)
            o[j] += w0 * win[j] + w1 * win[j + 1] + w2 * win[j + 2];
        }
        u32 pk[8];
#pragma unroll
        for (int q = 0; q < 8; ++q)
          pk[q] = (u32)f2b(fmaxf(o[2 * q], 0.f)) | ((u32)f2b(fmaxf(o[2 * q + 1], 0.f)) << 16);
        uint4* dst = (uint4*)(As + sl * ASTR + (hsel << 5) + wb);
        dst[0] = make_uint4(pk[0], pk[1], pk[2], pk[3]);
        dst[1] = make_uint4(pk[4], pk[5], pk[6], pk[7]);
      }
    }
#pragma unroll
    for (int p = 0; p < 4; ++p) {
      const int idx8 = t + (p << 8);
      const int n = idx8 >> 3, k8 = idx8 & 7;
      *(uint4*)(Bs + n * ASTR + (k8 << 3)) = bsv[p];
    }
    __syncthreads();
#pragma unroll
    for (int kc = 0; kc < 2; ++kc) {
      const int ko = (kc << 5) + (lq << 3);
      bf16x8 af[4], bfv[4];
#pragma unroll
      for (int im = 0; im < 4; ++im)
        af[im] = __builtin_bit_cast(bf16x8,
            *(const uint4*)(As + (wr * 64 + im * 16 + lr) * ASTR + ko));
#pragma unroll
      for (int jn = 0; jn < 4; ++jn)
        bfv[jn] = __builtin_bit_cast(bf16x8,
            *(const uint4*)(Bs + (wc * 64 + jn * 16 + lr) * ASTR + ko));
#pragma unroll
      for (int im = 0; im < 4; ++im)
#pragma unroll
        for (int jn = 0; jn < 4; ++jn)
          acc[im][jn] = __builtin_amdgcn_mfma_f32_16x16x32_bf16(
              af[im], bfv[jn], acc[im][jn], 0, 0, 0);
    }
  }
#pragma unroll
  for (int jn = 0; jn < 4; ++jn) {
    const int col = n0 + wc * 64 + jn * 16 + lr;
    const float lbv = lb[col];
#pragma unroll
    for (int im = 0; im < 4; ++im) {
      const int row0 = (mt << 7) + wr * 64 + im * 16 + (lq << 2);
#pragma unroll
      for (int r = 0; r < 4; ++r)
        out[(size_t)(row0 + r) * 512 + col] = acc[im][jn][r] + lbv;
    }
  }
}

extern "C" void kernel_launch(void* const* d_in, const int* in_sizes, int n_in,
                              void* d_out, int out_size, void* d_ws, size_t ws_size,
                              hipStream_t stream) {
  const float* img = (const float*)d_in[0];
  const float* cw  = (const float*)d_in[1];
  const float* cb  = (const float*)d_in[2];
  const float* lw  = (const float*)d_in[3];
  const float* lb  = (const float*)d_in[4];
  float* out = (float*)d_out;

  u16* btw = (u16*)((char*)d_ws + WS_BT);

  if (ws_size >= WS_NEED) {
    u16* cfp = (u16*)((char*)d_ws + WS_CF);
    u32* abp = (u32*)((char*)d_ws + WS_AB);
    prep3<<<dim3(2056), 256, 0, stream>>>(img, cw, cb, cfp, abp, lw, btw);
    gemm_k2<<<dim3(4, 512), 256, 0, stream>>>(cfp, abp, btw, lb, out);
  } else {
    transpose_w<<<dim3(8, 16), 256, 0, stream>>>(lw, btw);
    fused_fallback<<<dim3(4, 256), 256, 0, stream>>>(img, cw, cb, btw, lb, out);
  }
}

// Round 7
// 158.779 us; speedup vs baseline: 1.3843x; 1.3843x over previous
//
#include <hip/hip_runtime.h>
#include <cstdint>
#include <cstddef>

typedef unsigned short u16;
typedef unsigned int   u32;
typedef __attribute__((ext_vector_type(4))) float  f32x4;
typedef __attribute__((ext_vector_type(2))) float  f32x2;
typedef __attribute__((ext_vector_type(2))) u32    u32x2;
typedef __attribute__((ext_vector_type(8))) __bf16 bf16x8;

#define PSW   1056    // fallback: staged padded-image row width
#define ASTR  72      // fallback LDS row stride
#define CFW   4128    // Cfull row stride (elems); data cols 0..4119, zeros to 4127

// ws layout (bytes)
#define WS_BT  0u
#define WS_CF  1048576u                       // Bt: 512*1024*2
#define WS_AB  (1048576u + 16908288u)         // Cfull: 64*32*4128*2
#define WS_NEED (1048576u + 16908288u + 4194304u)  // + Abound: 64*32*512*4

static __device__ __forceinline__ float b2f(u32 u) {
  union { u32 i; float f; } c; c.i = u << 16; return c.f;
}
static __device__ __forceinline__ u16 f2b(float f) {
  union { float f; u32 i; } c; c.f = f;
  return (u16)((c.i + 0x7FFFu + ((c.i >> 16) & 1u)) >> 16);  // RNE
}

// async global->LDS DMA. LDS dest is WAVE-UNIFORM base + lane*size (m104).
static __device__ __forceinline__ void gl_lds16(const void* g, void* l) {
  __builtin_amdgcn_global_load_lds(
      (__attribute__((address_space(1))) unsigned int*)(void*)g,
      (__attribute__((address_space(3))) unsigned int*)l, 16, 0, 0);
}
static __device__ __forceinline__ void gl_lds4(const void* g, void* l) {
  __builtin_amdgcn_global_load_lds(
      (__attribute__((address_space(1))) unsigned int*)(void*)g,
      (__attribute__((address_space(3))) unsigned int*)l, 4, 0, 0);
}

// ---- standalone transpose (small-ws fallback path only)
__global__ __launch_bounds__(256) void transpose_w(const float* __restrict__ lw,
                                                   u16* __restrict__ bt) {
  __shared__ u16 tile[64][65];
  const int t  = threadIdx.x;
  const int c  = t & 63, r0 = t >> 6;
  const int n0 = blockIdx.x * 64;
  const int k0 = blockIdx.y * 64;
#pragma unroll
  for (int rr = 0; rr < 16; ++rr) {
    const int r = r0 * 16 + rr;
    tile[r][c] = f2b(lw[(size_t)(k0 + r) * 512 + n0 + c]);
  }
  __syncthreads();
#pragma unroll
  for (int rr = 0; rr < 16; ++rr) {
    const int r = r0 * 16 + rr;
    bt[(size_t)(n0 + r) * 1024 + k0 + c] = tile[c][r];
  }
}

// ---- kernel 1 (prep4): barrier-free conv+bias+relu -> Cfull + Abound.
// r6 postmortem: prep3's cost was NOT the conv (VALU 5%, HBM 5%) — it was the
// 8-block x 16-serial-tile transpose tail (Occupancy 12-16%: 248 CUs idle
// behind 8 blocks). Fix: transpose spread over 128 blocks x 1 tile (r1-style,
// ~2-4us, fully overlapped with conv). Conv body unchanged (r4/r6 verified):
// one block per (b,h) row, 2048 blocks = 8/CU, direct f32x4 global reads
// (3x vertical re-read L2-absorbed). XCD-bijective swizzle on conv ids.
__global__ __launch_bounds__(256) void prep4(
    const float* __restrict__ img, const float* __restrict__ cw,
    const float* __restrict__ cb, u16* __restrict__ cf, u32* __restrict__ ab,
    const float* __restrict__ lw, u16* __restrict__ bt)
{
  __shared__ __align__(16) u16 tile[64 * 65];   // transpose branch only (8.3KB)
  const int t  = threadIdx.x;
  const int id = blockIdx.x;

  if (id >= 2048) {
    // ---- transpose lin_w: 128 blocks, ONE 64x64 tile each (no serial tail)
    const int T  = id - 2048;                   // 0..127
    const int n0 = (T & 7) << 6, k0 = (T >> 3) << 6;
    const int c = t & 63, r0 = t >> 6;          // r0 in [0,4)
#pragma unroll
    for (int rr = 0; rr < 16; ++rr) {
      const int r = r0 * 16 + rr;
      tile[r * 65 + c] = f2b(lw[(size_t)(k0 + r) * 512 + n0 + c]);
    }
    __syncthreads();
#pragma unroll
    for (int rr = 0; rr < 16; ++rr) {
      const int r = r0 * 16 + rr;
      bt[(size_t)(n0 + r) * 1024 + k0 + c] = tile[c * 65 + r];
    }
    return;
  }

  const int wg = ((id & 7) << 8) + (id >> 3);   // bijective, 2048%8==0
  const int bb = wg >> 5, hh = wg & 31;
  const float* imgb = img + (size_t)bb * 32 * 4096;
  float w9[9];
#pragma unroll
  for (int q = 0; q < 9; ++q) w9[q] = cw[q];
  const float bias = cb[0];

  u16* cfrow = cf + (size_t)(bb * 32 + hh) * CFW;

  // chunk c: outputs x in [8c,8c+8); window = padded coords [8c-4,8c+12)
  // (coord p <-> img col p-12; p<12 / 4108<=p<4120 pad 1.0; p>=4120 slack 0.0;
  //  dead rows skip == add 0.0 == conv's vertical zero padding).
  auto CONV8 = [&](int c) {
    float o[8];
#pragma unroll
    for (int j = 0; j < 8; ++j) o[j] = bias;
#pragma unroll
    for (int dr = 0; dr < 3; ++dr) {
      const int hr = hh - 1 + dr;
      if (hr < 0 || hr > 31) continue;
      const float* rp = imgb + (ptrdiff_t)hr * 4096;
      float win[16];
      if (c >= 2 && c < 512) {                  // fully interior: 4x f32x4
        const f32x4* vp = (const f32x4*)(rp + (c << 3) - 16);
        *(f32x4*)&win[0]  = vp[0];
        *(f32x4*)&win[4]  = vp[1];
        *(f32x4*)&win[8]  = vp[2];
        *(f32x4*)&win[12] = vp[3];
      } else {                                  // edge: clamped scalar+select
#pragma unroll
        for (int k2 = 0; k2 < 16; ++k2) {
          const int p  = (c << 3) - 4 + k2;
          int ci = p - 12; ci = ci < 0 ? 0 : (ci > 4095 ? 4095 : ci);
          const float v = rp[ci];
          win[k2] = (p < 12) ? 1.0f : (p >= 4120 ? 0.0f : (p >= 4108 ? 1.0f : v));
        }
      }
      const float w0 = w9[dr * 3], w1 = w9[dr * 3 + 1], w2 = w9[dr * 3 + 2];
#pragma unroll
      for (int j = 0; j < 8; ++j)
        o[j] += w0 * win[j + 3] + w1 * win[j + 4] + w2 * win[j + 5];
    }
    u32 pk[4];
#pragma unroll
    for (int q = 0; q < 4; ++q)
      pk[q] = (u32)f2b(fmaxf(o[2 * q], 0.f)) |
              ((u32)f2b(fmaxf(o[2 * q + 1], 0.f)) << 16);
    *(uint4*)(cfrow + (c << 3)) = make_uint4(pk[0], pk[1], pk[2], pk[3]);
  };

  CONV8(t);
  CONV8(t + 256);
  if (t < 3) CONV8(512 + t);                    // outputs 4096..4119
  if (t == 3) *(uint4*)(cfrow + 4120) = make_uint4(0u, 0u, 0u, 0u);

  // Abound: slice s, col j=0 (coords 8s,8s+1) and j=31 (coords 8s+30,8s+31)
  u32* abrow = ab + (size_t)(bb * 32 + hh) * 512;
#pragma unroll
  for (int ss = 0; ss < 2; ++ss) {
    const int s = t + (ss << 8);
    float o0 = bias, o1 = bias;
#pragma unroll
    for (int dr = 0; dr < 3; ++dr) {
      const int hr = hh - 1 + dr;
      if (hr < 0 || hr > 31) continue;
      const float* rp = imgb + (ptrdiff_t)hr * 4096;
      float p0, p1, q0, q1;
      if (s >= 2)   { f32x2 v = *(const f32x2*)(rp + (s << 3) - 12); p0 = v.x; p1 = v.y; }
      else          { p0 = 1.0f; p1 = 1.0f; }
      if (s <= 509) { f32x2 v = *(const f32x2*)(rp + (s << 3) + 18); q0 = v.x; q1 = v.y; }
      else          { q0 = 1.0f; q1 = 1.0f; }
      o0 += w9[dr * 3 + 1] * p0 + w9[dr * 3 + 2] * p1;
      o1 += w9[dr * 3]     * q0 + w9[dr * 3 + 1] * q1;
    }
    abrow[s] = (u32)f2b(fmaxf(o0, 0.f)) | ((u32)f2b(fmaxf(o1, 0.f)) << 16);
  }
}

// ---- kernel 2: GEMM (M=32768,K=1024,N=512), M-tile 64, 2048 blocks = 8/CU.
// r1 vs r2 showed time ~ 1/(blocks per CU): inter-block phase-offset overlap
// hides the per-K-step vmcnt(0) drain. LDS 19072B, acc[2][4].
// XCD-aware bijective swizzle (2048 = 8*256): XCD x owns b in [8x,8x+8).
__global__ __launch_bounds__(256) void gemm_k2(
    const u16* __restrict__ cf, const u32* __restrict__ ab,
    const u16* __restrict__ bt, const float* __restrict__ lb,
    float* __restrict__ out)
{
  // Ps [2][544] u16 (2176B) | Ab32 [2][64] u32 (512B) | Bs 128x64 swz u16 (16384B)
  __shared__ __align__(16) char sm[2176 + 512 + 16384];
  u16* Ps   = (u16*)sm;
  u32* Ab32 = (u32*)(sm + 2176);
  u16* Bs   = (u16*)(sm + 2688);
  float* Cs = (float*)sm;          // epilogue reuse [32][132] = 16896B

  const int t  = threadIdx.x;
  const int orig = blockIdx.y * 4 + blockIdx.x;          // hw linear id
  const int wg   = ((orig & 7) << 8) + (orig >> 3);      // bijective, 2048%8==0
  const int nt = wg & 3, mt = wg >> 2;                   // mt in [0,512)
  const int b  = mt >> 3, sg = mt & 7;                   // 64-slice group sg
  const int n0 = nt << 7;
  const int w  = t >> 6, i = t & 63;
  const int wr = w >> 1, wc = w & 1;
  const int lq = i >> 4, lr = i & 15;

  // B staging: chunk q = w*256 + j*64 + i -> n = w*32 + j*8 + (i>>3), c = (i&7)^((i>>3)&7)
  const int cB = (i & 7) ^ ((i >> 3) & 7);
  const u16* btp = bt + (size_t)(n0 + (w << 5) + (i >> 3)) * 1024 + (cB << 3);
  u16* BsW = Bs + (w << 11);                    // wave-uniform, + j*512 elems per call

  // Ps staging: 136 chunks (2 rows x 68), q = t (t<136)
  const int rP  = (t >= 68) ? 1 : 0;
  const int ccP = t - 68 * rP;
  const u16* cfp = cf + (size_t)(b * 32 + rP) * CFW + (sg << 9) + (ccP << 3);
  u16* PsW = (u16*)((char*)Ps + (w << 10));     // wave-uniform byte base

  // Ab staging: 128 dwords, d = t (t<128): row t>>6, slice t&63
  const u32* abp = ab + (size_t)(b * 32 + (t >> 6)) * 512 + (sg << 6) + (t & 63);
  u32* AbW = Ab32 + (w << 6);                   // wave-uniform

  f32x4 acc[2][4];
#pragma unroll
  for (int a = 0; a < 2; ++a)
#pragma unroll
    for (int c = 0; c < 4; ++c) acc[a][c] = (f32x4)0.0f;

  for (int kk = 0; kk < 16; ++kk) {
    __syncthreads();                 // all waves done reading prev tiles
    gl_lds16(btp,              BsW);
    gl_lds16(btp +  8 * 1024,  BsW + 512);
    gl_lds16(btp + 16 * 1024,  BsW + 1024);
    gl_lds16(btp + 24 * 1024,  BsW + 1536);
    if (t < 136) gl_lds16(cfp, PsW);
    if (t < 128) gl_lds4(abp, AbW);
    btp += 64; cfp += 2 * CFW; abp += 1024;
    __syncthreads();                 // drains vmcnt(0): DMA complete

#pragma unroll
    for (int kc = 0; kc < 2; ++kc) {
      const int bswz = (((kc << 2) + lq) ^ (lr & 7)) << 3;
      bf16x8 af[2], bfv[4];
#pragma unroll
      for (int im = 0; im < 2; ++im) {
        const int ml = wr * 32 + im * 16 + lr;
        af[im] = __builtin_bit_cast(bf16x8,
            *(const uint4*)(Ps + kc * 544 + ((ml + lq) << 3)));
        const u32 a32 = Ab32[kc * 64 + ml];    // same addr for 4 lq -> broadcast
        union { u16 u; __bf16 h; } lo, hi;
        lo.u = (u16)(a32 & 0xffffu); hi.u = (u16)(a32 >> 16);
        if (lq == 0) af[im][0] = lo.h;         // slice col j=0
        if (lq == 3) af[im][7] = hi.h;         // slice col j=31
      }
#pragma unroll
      for (int jn = 0; jn < 4; ++jn) {
        const int n = wc * 64 + jn * 16 + lr;
        bfv[jn] = __builtin_bit_cast(bf16x8, *(const uint4*)(Bs + (n << 6) + bswz));
      }
#pragma unroll
      for (int im = 0; im < 2; ++im)
#pragma unroll
        for (int jn = 0; jn < 4; ++jn)
          acc[im][jn] = __builtin_amdgcn_mfma_f32_16x16x32_bf16(
              af[im], bfv[jn], acc[im][jn], 0, 0, 0);
    }
  }

  // epilogue: +lin_b, LDS transpose, coalesced float4 row stores
  float lbv[4];
#pragma unroll
  for (int jn = 0; jn < 4; ++jn) lbv[jn] = lb[n0 + wc * 64 + jn * 16 + lr];

  const int erow = t >> 3, ecol = (t & 7) << 4;
  const int grow_base = (mt << 6) + ((erow >> 4) * 32) + (erow & 15);

#pragma unroll
  for (int im = 0; im < 2; ++im) {
    __syncthreads();
#pragma unroll
    for (int jn = 0; jn < 4; ++jn) {
      const int cl = wc * 64 + jn * 16 + lr;
#pragma unroll
      for (int r = 0; r < 4; ++r)
        Cs[(wr * 16 + lq * 4 + r) * 132 + cl] = acc[im][jn][r] + lbv[jn];
    }
    __syncthreads();
    const size_t grow = (size_t)(grow_base + im * 16);
    float* orow = out + grow * 512 + n0 + ecol;
    const float* crow = Cs + erow * 132 + ecol;
#pragma unroll
    for (int p = 0; p < 4; ++p)
      *(f32x4*)(orow + p * 4) = *(const f32x4*)(crow + p * 4);
  }
}

// ================= small-ws fallback (needs only 1MB ws) =================
__global__ __launch_bounds__(256) void fused_fallback(
    const float* __restrict__ img, const float* __restrict__ cw,
    const float* __restrict__ cb, const u16* __restrict__ bt,
    const float* __restrict__ lb, float* __restrict__ out)
{
  __shared__ __align__(16) u16 Ps[4 * PSW];
  __shared__ __align__(16) u16 As[128 * ASTR];
  __shared__ __align__(16) u16 Bs[128 * ASTR];
  const int t = threadIdx.x, nt = blockIdx.x, mt = blockIdx.y;
  const int b = mt >> 2, s0 = (mt & 3) << 7, X0 = s0 << 3, n0 = nt << 7;
  const float* imgb = img + (size_t)b * 32 * 4096;
  float cwf[9];
#pragma unroll
  for (int q = 0; q < 9; ++q) cwf[q] = cw[q];
  const float bias = cb[0];
  const int wv = t >> 6, l = t & 63;
  const int wr = wv >> 1, wc = wv & 1, lq = l >> 4, lr = l & 15;
  const int sl = t >> 1, hsel = t & 1;
  f32x4 acc[4][4];
#pragma unroll
  for (int a = 0; a < 4; ++a)
#pragma unroll
    for (int c = 0; c < 4; ++c) acc[a][c] = (f32x4)0.0f;
  for (int kk = 0; kk < 16; ++kk) {
    const int h0 = kk << 1;
    __syncthreads();
    uint4 bsv[4];
#pragma unroll
    for (int p = 0; p < 4; ++p) {
      const int idx8 = t + (p << 8);
      const int n = idx8 >> 3, k8 = idx8 & 7;
      bsv[p] = *(const uint4*)(bt + (size_t)(n0 + n) * 1024 + (kk << 6) + (k8 << 3));
    }
    for (int idx = t; idx < 4 * PSW; idx += 256) {
      const int r = idx / PSW, xi = idx - r * PSW;
      const int h = h0 - 1 + r, x = X0 - 1 + xi;
      u16 v = 0;
      if (h >= 0 && h < 32 && x >= 0 && x < 4120)
        v = (x < 12 || x >= 4108) ? (u16)0x3F80 : f2b(imgb[h * 4096 + (x - 12)]);
      Ps[idx] = v;
    }
    __syncthreads();
    {
      const int pbase = (sl << 3);
#pragma unroll
      for (int wb = 0; wb < 32; wb += 16) {
        float o[16];
#pragma unroll
        for (int j = 0; j < 16; ++j) o[j] = bias;
#pragma unroll
        for (int dr = 0; dr < 3; ++dr) {
          const u16* p = Ps + (hsel + dr) * PSW + pbase + wb;
          const uint4 va = *(const uint4*)p;
          const uint4 vb = *(const uint4*)(p + 8);
          const u32   vc = *(const u32*)(p + 16);
          float win[18];
          win[0] = b2f(va.x & 0xffffu); win[1] = b2f(va.x >> 16);
          win[2] = b2f(va.y & 0xffffu); win[3] = b2f(va.y >> 16);
          win[4] = b2f(va.z & 0xffffu); win[5] = b2f(va.z >> 16);
          win[6] = b2f(va.w & 0xffffu); win[7] = b2f(va.w >> 16);
          win[8] = b2f(vb.x & 0xffffu); win[9] = b2f(vb.x >> 16);
          win[10] = b2f(vb.y & 0xffffu); win[11] = b2f(vb.y >> 16);
          win[12] = b2f(vb.z & 0xffffu); win[13] = b2f(vb.z >> 16);
          win[14] = b2f(vb.w & 0xffffu); win[15] = b2f(vb.w >> 16);
          win[16] = b2f(vc & 0xffffu);   win[17] = b2f(vc >> 16);
          if (wb == 0) win[0] = 0.f; else win[17] = 0.f;
          const float w0 = cwf[dr * 3], w1 = cwf[dr * 3 + 1], w2 = cwf[dr * 3 + 2];
#pragma unroll
          for (int j = 0; j < 16; ++j)
            o[j] += w0 * win[j] + w1 * win[j + 1] + w2 * win[j + 2];
        }
        u32 pk[8];
#pragma unroll
        for (int q = 0; q < 8; ++q)
          pk[q] = (u32)f2b(fmaxf(o[2 * q], 0.f)) | ((u32)f2b(fmaxf(o[2 * q + 1], 0.f)) << 16);
        uint4* dst = (uint4*)(As + sl * ASTR + (hsel << 5) + wb);
        dst[0] = make_uint4(pk[0], pk[1], pk[2], pk[3]);
        dst[1] = make_uint4(pk[4], pk[5], pk[6], pk[7]);
      }
    }
#pragma unroll
    for (int p = 0; p < 4; ++p) {
      const int idx8 = t + (p << 8);
      const int n = idx8 >> 3, k8 = idx8 & 7;
      *(uint4*)(Bs + n * ASTR + (k8 << 3)) = bsv[p];
    }
    __syncthreads();
#pragma unroll
    for (int kc = 0; kc < 2; ++kc) {
      const int ko = (kc << 5) + (lq << 3);
      bf16x8 af[4], bfv[4];
#pragma unroll
      for (int im = 0; im < 4; ++im)
        af[im] = __builtin_bit_cast(bf16x8,
            *(const uint4*)(As + (wr * 64 + im * 16 + lr) * ASTR + ko));
#pragma unroll
      for (int jn = 0; jn < 4; ++jn)
        bfv[jn] = __builtin_bit_cast(bf16x8,
            *(const uint4*)(Bs + (wc * 64 + jn * 16 + lr) * ASTR + ko));
#pragma unroll
      for (int im = 0; im < 4; ++im)
#pragma unroll
        for (int jn = 0; jn < 4; ++jn)
          acc[im][jn] = __builtin_amdgcn_mfma_f32_16x16x32_bf16(
              af[im], bfv[jn], acc[im][jn], 0, 0, 0);
    }
  }
#pragma unroll
  for (int jn = 0; jn < 4; ++jn) {
    const int col = n0 + wc * 64 + jn * 16 + lr;
    const float lbv = lb[col];
#pragma unroll
    for (int im = 0; im < 4; ++im) {
      const int row0 = (mt << 7) + wr * 64 + im * 16 + (lq << 2);
#pragma unroll
      for (int r = 0; r < 4; ++r)
        out[(size_t)(row0 + r) * 512 + col] = acc[im][jn][r] + lbv;
    }
  }
}

extern "C" void kernel_launch(void* const* d_in, const int* in_sizes, int n_in,
                              void* d_out, int out_size, void* d_ws, size_t ws_size,
                              hipStream_t stream) {
  const float* img = (const float*)d_in[0];
  const float* cw  = (const float*)d_in[1];
  const float* cb  = (const float*)d_in[2];
  const float* lw  = (const float*)d_in[3];
  const float* lb  = (const float*)d_in[4];
  float* out = (float*)d_out;

  u16* btw = (u16*)((char*)d_ws + WS_BT);

  if (ws_size >= WS_NEED) {
    u16* cfp = (u16*)((char*)d_ws + WS_CF);
    u32* abp = (u32*)((char*)d_ws + WS_AB);
    prep4<<<dim3(2176), 256, 0, stream>>>(img, cw, cb, cfp, abp, lw, btw);
    gemm_k2<<<dim3(4, 512), 256, 0, stream>>>(cfp, abp, btw, lb, out);
  } else {
    transpose_w<<<dim3(8, 16), 256, 0, stream>>>(lw, btw);
    fused_fallback<<<dim3(4, 256), 256, 0, stream>>>(img, cw, cb, btw, lb, out);
  }
}

// Round 8
// 149.456 us; speedup vs baseline: 1.4706x; 1.0624x over previous
//
#include <hip/hip_runtime.h>
#include <cstdint>
#include <cstddef>

typedef unsigned short u16;
typedef unsigned int   u32;
typedef __attribute__((ext_vector_type(4))) float  f32x4;
typedef __attribute__((ext_vector_type(2))) float  f32x2;
typedef __attribute__((ext_vector_type(2))) u32    u32x2;
typedef __attribute__((ext_vector_type(8))) __bf16 bf16x8;

#define PSW   1056    // fallback: staged padded-image row width
#define ASTR  72      // fallback LDS row stride
#define CFW   4128    // Cfull row stride (elems); data cols 0..4119, zeros to 4127
#define LROW  4128    // prep5: LDS row floats; padded coord p at idx p+4

// ws layout (bytes)
#define WS_BT  0u
#define WS_CF  1048576u                       // Bt: 512*1024*2
#define WS_AB  (1048576u + 16908288u)         // Cfull: 64*32*4128*2
#define WS_NEED (1048576u + 16908288u + 4194304u)  // + Abound: 64*32*512*4

static __device__ __forceinline__ float b2f(u32 u) {
  union { u32 i; float f; } c; c.i = u << 16; return c.f;
}
static __device__ __forceinline__ u16 f2b(float f) {
  union { float f; u32 i; } c; c.f = f;
  return (u16)((c.i + 0x7FFFu + ((c.i >> 16) & 1u)) >> 16);  // RNE
}

// async global->LDS DMA. LDS dest is WAVE-UNIFORM base + lane*size (m104).
static __device__ __forceinline__ void gl_lds16(const void* g, void* l) {
  __builtin_amdgcn_global_load_lds(
      (__attribute__((address_space(1))) unsigned int*)(void*)g,
      (__attribute__((address_space(3))) unsigned int*)l, 16, 0, 0);
}
static __device__ __forceinline__ void gl_lds4(const void* g, void* l) {
  __builtin_amdgcn_global_load_lds(
      (__attribute__((address_space(1))) unsigned int*)(void*)g,
      (__attribute__((address_space(3))) unsigned int*)l, 4, 0, 0);
}

// ---- standalone transpose (small-ws fallback path only)
__global__ __launch_bounds__(256) void transpose_w(const float* __restrict__ lw,
                                                   u16* __restrict__ bt) {
  __shared__ u16 tile[64][65];
  const int t  = threadIdx.x;
  const int c  = t & 63, r0 = t >> 6;
  const int n0 = blockIdx.x * 64;
  const int k0 = blockIdx.y * 64;
#pragma unroll
  for (int rr = 0; rr < 16; ++rr) {
    const int r = r0 * 16 + rr;
    tile[r][c] = f2b(lw[(size_t)(k0 + r) * 512 + n0 + c]);
  }
  __syncthreads();
#pragma unroll
  for (int rr = 0; rr < 16; ++rr) {
    const int r = r0 * 16 + rr;
    bt[(size_t)(n0 + r) * 1024 + k0 + c] = tile[c][r];
  }
}

// ---- kernel 1 (prep5): conv+bias+relu -> Cfull + Abound.
// r7 postmortem: prep4's direct-global conv was VMEM-transaction-bound (lane
// stride 128B -> 64 cache lines per load instr, VALUBusy 5%); prep2's LDS conv
// was fast but serialized by its 8-row ring + transpose tail. prep5 combines
// the fixes: one block per (b,h) row (2048 blocks, no serial loop), 3 rows
// staged COALESCED via global_load_lds (48KB LDS, 3 blk/CU), ONE barrier,
// lane-consecutive CONV4 from LDS (conflict-free ds_read_b128), Abound from
// staged pads. Transpose: 128 parallel blocks (r7-verified). XCD-bijective
// swizzle keeps h-adjacent blocks on one XCD (L2-hot 3x vertical re-read).
__global__ __launch_bounds__(256) void prep5(
    const float* __restrict__ img, const float* __restrict__ cw,
    const float* __restrict__ cb, u16* __restrict__ cf, u32* __restrict__ ab,
    const float* __restrict__ lw, u16* __restrict__ bt)
{
  __shared__ __align__(16) float R[3][LROW];    // 49.5 KB; coord p at idx p+4
  const int t  = threadIdx.x;
  const int id = blockIdx.x;

  if (id >= 2048) {
    // ---- transpose lin_w: 128 blocks, ONE 64x64 tile each
    u16* tile = (u16*)&R[0][0];
    const int T  = id - 2048;                   // 0..127
    const int n0 = (T & 7) << 6, k0 = (T >> 3) << 6;
    const int c = t & 63, r0 = t >> 6;          // r0 in [0,4)
#pragma unroll
    for (int rr = 0; rr < 16; ++rr) {
      const int r = r0 * 16 + rr;
      tile[r * 65 + c] = f2b(lw[(size_t)(k0 + r) * 512 + n0 + c]);
    }
    __syncthreads();
#pragma unroll
    for (int rr = 0; rr < 16; ++rr) {
      const int r = r0 * 16 + rr;
      bt[(size_t)(n0 + r) * 1024 + k0 + c] = tile[c * 65 + r];
    }
    return;
  }

  const int wg = ((id & 7) << 8) + (id >> 3);   // bijective, 2048%8==0
  const int bb = wg >> 5, hh = wg & 31;
  const float* imgb = img + (size_t)bb * 32 * 4096;
  const int w4id = t >> 6;                      // wave id (uniform)

  // stage rows hh-1, hh, hh+1. img col c at idx c+16 (= coord c+12 at +4).
  // 4096 floats = 1024 chunks of 16B; 4 DMA/thread, wave-uniform LDS base.
#pragma unroll
  for (int r = 0; r < 3; ++r) {
    float* Rr = &R[r][0];
    const int hr = hh - 1 + r;
    if (hr >= 0 && hr <= 31) {
      const float* src = imgb + (ptrdiff_t)hr * 4096;
#pragma unroll
      for (int p = 0; p < 4; ++p)
        gl_lds16(src + ((t + (p << 8)) << 2),
                 Rr + 16 + (w4id << 8) + (p << 10));
      // edge fixups (disjoint from DMA region 16..4111)
      if (t < 4)       Rr[t] = 0.0f;            // idx 0..3 slack
      else if (t < 16) Rr[t] = 1.0f;            // coords 0..11 pad
      else if (t < 28) Rr[4096 + t] = 1.0f;     // idx 4112..4123: coords 4108..4119
      else if (t < 32) Rr[4096 + t] = 0.0f;     // idx 4124..4127 slack
    } else {
      // dead row: zero all 4128 floats
#pragma unroll
      for (int p = 0; p < 4; ++p)
        *(f32x4*)(Rr + ((t + (p << 8)) << 2)) = (f32x4)0.0f;
      if (t < 8) *(f32x4*)(Rr + 4096 + (t << 2)) = (f32x4)0.0f;
    }
  }
  __syncthreads();                              // drains DMA (vmcnt 0)

  float w9[9];
#pragma unroll
  for (int q = 0; q < 9; ++q) w9[q] = cw[q];
  const float bias = cb[0];
  u16* cfrow = cf + (size_t)(bb * 32 + hh) * CFW;
  if (t == 0) *(uint4*)(cfrow + 4120) = make_uint4(0u, 0u, 0u, 0u);

  const float* R0 = &R[0][0];
  const float* R1 = &R[1][0];
  const float* R2 = &R[2][0];

  // out x = 4*c4 + j, j=0..3; taps LDS idx [4c4+3 .. 4c4+8] (prep2-verified)
  auto CONV4 = [&](int c4) {
    const int w4 = c4 << 2;
    const f32x4 a0 = *(const f32x4*)(R0 + w4), b0 = *(const f32x4*)(R0 + w4 + 4);
    const float c0 = R0[w4 + 8];
    const f32x4 a1 = *(const f32x4*)(R1 + w4), b1 = *(const f32x4*)(R1 + w4 + 4);
    const float c1 = R1[w4 + 8];
    const f32x4 a2 = *(const f32x4*)(R2 + w4), b2 = *(const f32x4*)(R2 + w4 + 4);
    const float c2 = R2[w4 + 8];
    float o0 = bias, o1 = bias, o2 = bias, o3 = bias;
    o0 += w9[0] * a0.w + w9[1] * b0.x + w9[2] * b0.y;
    o1 += w9[0] * b0.x + w9[1] * b0.y + w9[2] * b0.z;
    o2 += w9[0] * b0.y + w9[1] * b0.z + w9[2] * b0.w;
    o3 += w9[0] * b0.z + w9[1] * b0.w + w9[2] * c0;
    o0 += w9[3] * a1.w + w9[4] * b1.x + w9[5] * b1.y;
    o1 += w9[3] * b1.x + w9[4] * b1.y + w9[5] * b1.z;
    o2 += w9[3] * b1.y + w9[4] * b1.z + w9[5] * b1.w;
    o3 += w9[3] * b1.z + w9[4] * b1.w + w9[5] * c1;
    o0 += w9[6] * a2.w + w9[7] * b2.x + w9[8] * b2.y;
    o1 += w9[6] * b2.x + w9[7] * b2.y + w9[8] * b2.z;
    o2 += w9[6] * b2.y + w9[7] * b2.z + w9[8] * b2.w;
    o3 += w9[6] * b2.z + w9[7] * b2.w + w9[8] * c2;
    u32x2 pk;
    pk.x = (u32)f2b(fmaxf(o0, 0.f)) | ((u32)f2b(fmaxf(o1, 0.f)) << 16);
    pk.y = (u32)f2b(fmaxf(o2, 0.f)) | ((u32)f2b(fmaxf(o3, 0.f)) << 16);
    *(u32x2*)(cfrow + (c4 << 2)) = pk;
  };

  for (int c4 = t; c4 < 1030; c4 += 256) CONV4(c4);

  // Abound: slice s: j=0 = w1*P[8s]+w2*P[8s+1] -> L[8s+4],L[8s+5];
  //                  j=31 = w0*P[8s+30]+w1*P[8s+31] -> L[8s+34],L[8s+35].
  // Pads/slack staged in LDS -> no edge selects (coords<12 & >=4108 are 1.0).
  u32* abrow = ab + (size_t)(bb * 32 + hh) * 512;
#pragma unroll
  for (int ss = 0; ss < 2; ++ss) {
    const int s  = t + (ss << 8);
    const int X0 = (s << 3) + 4;
    float o0 = bias, o1 = bias;
    o0 += w9[1] * R0[X0]      + w9[2] * R0[X0 + 1];
    o1 += w9[0] * R0[X0 + 30] + w9[1] * R0[X0 + 31];
    o0 += w9[4] * R1[X0]      + w9[5] * R1[X0 + 1];
    o1 += w9[3] * R1[X0 + 30] + w9[4] * R1[X0 + 31];
    o0 += w9[7] * R2[X0]      + w9[8] * R2[X0 + 1];
    o1 += w9[6] * R2[X0 + 30] + w9[7] * R2[X0 + 31];
    abrow[s] = (u32)f2b(fmaxf(o0, 0.f)) | ((u32)f2b(fmaxf(o1, 0.f)) << 16);
  }
}

// ---- kernel 2: GEMM (M=32768,K=1024,N=512), M-tile 64, 2048 blocks = 8/CU.
// r1 vs r2 showed time ~ 1/(blocks per CU): inter-block phase-offset overlap
// hides the per-K-step vmcnt(0) drain. LDS 19072B, acc[2][4].
// XCD-aware bijective swizzle (2048 = 8*256): XCD x owns b in [8x,8x+8).
__global__ __launch_bounds__(256) void gemm_k2(
    const u16* __restrict__ cf, const u32* __restrict__ ab,
    const u16* __restrict__ bt, const float* __restrict__ lb,
    float* __restrict__ out)
{
  // Ps [2][544] u16 (2176B) | Ab32 [2][64] u32 (512B) | Bs 128x64 swz u16 (16384B)
  __shared__ __align__(16) char sm[2176 + 512 + 16384];
  u16* Ps   = (u16*)sm;
  u32* Ab32 = (u32*)(sm + 2176);
  u16* Bs   = (u16*)(sm + 2688);
  float* Cs = (float*)sm;          // epilogue reuse [32][132] = 16896B

  const int t  = threadIdx.x;
  const int orig = blockIdx.y * 4 + blockIdx.x;          // hw linear id
  const int wg   = ((orig & 7) << 8) + (orig >> 3);      // bijective, 2048%8==0
  const int nt = wg & 3, mt = wg >> 2;                   // mt in [0,512)
  const int b  = mt >> 3, sg = mt & 7;                   // 64-slice group sg
  const int n0 = nt << 7;
  const int w  = t >> 6, i = t & 63;
  const int wr = w >> 1, wc = w & 1;
  const int lq = i >> 4, lr = i & 15;

  // B staging: chunk q = w*256 + j*64 + i -> n = w*32 + j*8 + (i>>3), c = (i&7)^((i>>3)&7)
  const int cB = (i & 7) ^ ((i >> 3) & 7);
  const u16* btp = bt + (size_t)(n0 + (w << 5) + (i >> 3)) * 1024 + (cB << 3);
  u16* BsW = Bs + (w << 11);                    // wave-uniform, + j*512 elems per call

  // Ps staging: 136 chunks (2 rows x 68), q = t (t<136)
  const int rP  = (t >= 68) ? 1 : 0;
  const int ccP = t - 68 * rP;
  const u16* cfp = cf + (size_t)(b * 32 + rP) * CFW + (sg << 9) + (ccP << 3);
  u16* PsW = (u16*)((char*)Ps + (w << 10));     // wave-uniform byte base

  // Ab staging: 128 dwords, d = t (t<128): row t>>6, slice t&63
  const u32* abp = ab + (size_t)(b * 32 + (t >> 6)) * 512 + (sg << 6) + (t & 63);
  u32* AbW = Ab32 + (w << 6);                   // wave-uniform

  f32x4 acc[2][4];
#pragma unroll
  for (int a = 0; a < 2; ++a)
#pragma unroll
    for (int c = 0; c < 4; ++c) acc[a][c] = (f32x4)0.0f;

  for (int kk = 0; kk < 16; ++kk) {
    __syncthreads();                 // all waves done reading prev tiles
    gl_lds16(btp,              BsW);
    gl_lds16(btp +  8 * 1024,  BsW + 512);
    gl_lds16(btp + 16 * 1024,  BsW + 1024);
    gl_lds16(btp + 24 * 1024,  BsW + 1536);
    if (t < 136) gl_lds16(cfp, PsW);
    if (t < 128) gl_lds4(abp, AbW);
    btp += 64; cfp += 2 * CFW; abp += 1024;
    __syncthreads();                 // drains vmcnt(0): DMA complete

#pragma unroll
    for (int kc = 0; kc < 2; ++kc) {
      const int bswz = (((kc << 2) + lq) ^ (lr & 7)) << 3;
      bf16x8 af[2], bfv[4];
#pragma unroll
      for (int im = 0; im < 2; ++im) {
        const int ml = wr * 32 + im * 16 + lr;
        af[im] = __builtin_bit_cast(bf16x8,
            *(const uint4*)(Ps + kc * 544 + ((ml + lq) << 3)));
        const u32 a32 = Ab32[kc * 64 + ml];    // same addr for 4 lq -> broadcast
        union { u16 u; __bf16 h; } lo, hi;
        lo.u = (u16)(a32 & 0xffffu); hi.u = (u16)(a32 >> 16);
        if (lq == 0) af[im][0] = lo.h;         // slice col j=0
        if (lq == 3) af[im][7] = hi.h;         // slice col j=31
      }
#pragma unroll
      for (int jn = 0; jn < 4; ++jn) {
        const int n = wc * 64 + jn * 16 + lr;
        bfv[jn] = __builtin_bit_cast(bf16x8, *(const uint4*)(Bs + (n << 6) + bswz));
      }
#pragma unroll
      for (int im = 0; im < 2; ++im)
#pragma unroll
        for (int jn = 0; jn < 4; ++jn)
          acc[im][jn] = __builtin_amdgcn_mfma_f32_16x16x32_bf16(
              af[im], bfv[jn], acc[im][jn], 0, 0, 0);
    }
  }

  // epilogue: +lin_b, LDS transpose, coalesced float4 row stores
  float lbv[4];
#pragma unroll
  for (int jn = 0; jn < 4; ++jn) lbv[jn] = lb[n0 + wc * 64 + jn * 16 + lr];

  const int erow = t >> 3, ecol = (t & 7) << 4;
  const int grow_base = (mt << 6) + ((erow >> 4) * 32) + (erow & 15);

#pragma unroll
  for (int im = 0; im < 2; ++im) {
    __syncthreads();
#pragma unroll
    for (int jn = 0; jn < 4; ++jn) {
      const int cl = wc * 64 + jn * 16 + lr;
#pragma unroll
      for (int r = 0; r < 4; ++r)
        Cs[(wr * 16 + lq * 4 + r) * 132 + cl] = acc[im][jn][r] + lbv[jn];
    }
    __syncthreads();
    const size_t grow = (size_t)(grow_base + im * 16);
    float* orow = out + grow * 512 + n0 + ecol;
    const float* crow = Cs + erow * 132 + ecol;
#pragma unroll
    for (int p = 0; p < 4; ++p)
      *(f32x4*)(orow + p * 4) = *(const f32x4*)(crow + p * 4);
  }
}

// ================= small-ws fallback (needs only 1MB ws) =================
__global__ __launch_bounds__(256) void fused_fallback(
    const float* __restrict__ img, const float* __restrict__ cw,
    const float* __restrict__ cb, const u16* __restrict__ bt,
    const float* __restrict__ lb, float* __restrict__ out)
{
  __shared__ __align__(16) u16 Ps[4 * PSW];
  __shared__ __align__(16) u16 As[128 * ASTR];
  __shared__ __align__(16) u16 Bs[128 * ASTR];
  const int t = threadIdx.x, nt = blockIdx.x, mt = blockIdx.y;
  const int b = mt >> 2, s0 = (mt & 3) << 7, X0 = s0 << 3, n0 = nt << 7;
  const float* imgb = img + (size_t)b * 32 * 4096;
  float cwf[9];
#pragma unroll
  for (int q = 0; q < 9; ++q) cwf[q] = cw[q];
  const float bias = cb[0];
  const int wv = t >> 6, l = t & 63;
  const int wr = wv >> 1, wc = wv & 1, lq = l >> 4, lr = l & 15;
  const int sl = t >> 1, hsel = t & 1;
  f32x4 acc[4][4];
#pragma unroll
  for (int a = 0; a < 4; ++a)
#pragma unroll
    for (int c = 0; c < 4; ++c) acc[a][c] = (f32x4)0.0f;
  for (int kk = 0; kk < 16; ++kk) {
    const int h0 = kk << 1;
    __syncthreads();
    uint4 bsv[4];
#pragma unroll
    for (int p = 0; p < 4; ++p) {
      const int idx8 = t + (p << 8);
      const int n = idx8 >> 3, k8 = idx8 & 7;
      bsv[p] = *(const uint4*)(bt + (size_t)(n0 + n) * 1024 + (kk << 6) + (k8 << 3));
    }
    for (int idx = t; idx < 4 * PSW; idx += 256) {
      const int r = idx / PSW, xi = idx - r * PSW;
      const int h = h0 - 1 + r, x = X0 - 1 + xi;
      u16 v = 0;
      if (h >= 0 && h < 32 && x >= 0 && x < 4120)
        v = (x < 12 || x >= 4108) ? (u16)0x3F80 : f2b(imgb[h * 4096 + (x - 12)]);
      Ps[idx] = v;
    }
    __syncthreads();
    {
      const int pbase = (sl << 3);
#pragma unroll
      for (int wb = 0; wb < 32; wb += 16) {
        float o[16];
#pragma unroll
        for (int j = 0; j < 16; ++j) o[j] = bias;
#pragma unroll
        for (int dr = 0; dr < 3; ++dr) {
          const u16* p = Ps + (hsel + dr) * PSW + pbase + wb;
          const uint4 va = *(const uint4*)p;
          const uint4 vb = *(const uint4*)(p + 8);
          const u32   vc = *(const u32*)(p + 16);
          float win[18];
          win[0] = b2f(va.x & 0xffffu); win[1] = b2f(va.x >> 16);
          win[2] = b2f(va.y & 0xffffu); win[3] = b2f(va.y >> 16);
          win[4] = b2f(va.z & 0xffffu); win[5] = b2f(va.z >> 16);
          win[6] = b2f(va.w & 0xffffu); win[7] = b2f(va.w >> 16);
          win[8] = b2f(vb.x & 0xffffu); win[9] = b2f(vb.x >> 16);
          win[10] = b2f(vb.y & 0xffffu); win[11] = b2f(vb.y >> 16);
          win[12] = b2f(vb.z & 0xffffu); win[13] = b2f(vb.z >> 16);
          win[14] = b2f(vb.w & 0xffffu); win[15] = b2f(vb.w >> 16);
          win[16] = b2f(vc & 0xffffu);   win[17] = b2f(vc >> 16);
          if (wb == 0) win[0] = 0.f; else win[17] = 0.f;
          const float w0 = cwf[dr * 3], w1 = cwf[dr * 3 + 1], w2 = cwf[dr * 3 + 2];
#pragma unroll
          for (int j = 0; j < 16; ++j)
            o[j] += w0 * win[j] + w1 * win[j + 1] + w2 * win[j + 2];
        }
        u32 pk[8];
#pragma unroll
        for (int q = 0; q < 8; ++q)
          pk[q] = (u32)f2b(fmaxf(o[2 * q], 0.f)) | ((u32)f2b(fmaxf(o[2 * q + 1], 0.f)) << 16);
        uint4* dst = (uint4*)(As + sl * ASTR + (hsel << 5) + wb);
        dst[0] = make_uint4(pk[0], pk[1], pk[2], pk[3]);
        dst[1] = make_uint4(pk[4], pk[5], pk[6], pk[7]);
      }
    }
#pragma unroll
    for (int p = 0; p < 4; ++p) {
      const int idx8 = t + (p << 8);
      const int n = idx8 >> 3, k8 = idx8 & 7;
      *(uint4*)(Bs + n * ASTR + (k8 << 3)) = bsv[p];
    }
    __syncthreads();
#pragma unroll
    for (int kc = 0; kc < 2; ++kc) {
      const int ko = (kc << 5) + (lq << 3);
      bf16x8 af[4], bfv[4];
#pragma unroll
      for (int im = 0; im < 4; ++im)
        af[im] = __builtin_bit_cast(bf16x8,
            *(const uint4*)(As + (wr * 64 + im * 16 + lr) * ASTR + ko));
#pragma unroll
      for (int jn = 0; jn < 4; ++jn)
        bfv[jn] = __builtin_bit_cast(bf16x8,
            *(const uint4*)(Bs + (wc * 64 + jn * 16 + lr) * ASTR + ko));
#pragma unroll
      for (int im = 0; im < 4; ++im)
#pragma unroll
        for (int jn = 0; jn < 4; ++jn)
          acc[im][jn] = __builtin_amdgcn_mfma_f32_16x16x32_bf16(
              af[im], bfv[jn], acc[im][jn], 0, 0, 0);
    }
  }
#pragma unroll
  for (int jn = 0; jn < 4; ++jn) {
    const int col = n0 + wc * 64 + jn * 16 + lr;
    const float lbv = lb[col];
#pragma unroll
    for (int im = 0; im < 4; ++im) {
      const int row0 = (mt << 7) + wr * 64 + im * 16 + (lq << 2);
#pragma unroll
      for (int r = 0; r < 4; ++r)
        out[(size_t)(row0 + r) * 512 + col] = acc[im][jn][r] + lbv;
    }
  }
}

extern "C" void kernel_launch(void* const* d_in, const int* in_sizes, int n_in,
                              void* d_out, int out_size, void* d_ws, size_t ws_size,
                              hipStream_t stream) {
  const float* img = (const float*)d_in[0];
  const float* cw  = (const float*)d_in[1];
  const float* cb  = (const float*)d_in[2];
  const float* lw  = (const float*)d_in[3];
  const float* lb  = (const float*)d_in[4];
  float* out = (float*)d_out;

  u16* btw = (u16*)((char*)d_ws + WS_BT);

  if (ws_size >= WS_NEED) {
    u16* cfp = (u16*)((char*)d_ws + WS_CF);
    u32* abp = (u32*)((char*)d_ws + WS_AB);
    prep5<<<dim3(2176), 256, 0, stream>>>(img, cw, cb, cfp, abp, lw, btw);
    gemm_k2<<<dim3(4, 512), 256, 0, stream>>>(cfp, abp, btw, lb, out);
  } else {
    transpose_w<<<dim3(8, 16), 256, 0, stream>>>(lw, btw);
    fused_fallback<<<dim3(4, 256), 256, 0, stream>>>(img, cw, cb, btw, lb, out);
  }
}